// Round 6
// baseline (199.625 us; speedup 1.0000x reference)
//
#include <hip/hip_runtime.h>
#include <hip/hip_bf16.h>

#define T_TOK 8192
#define DDIM 1024
#define HDIM 1024
#define NEXP 8
#define KTOP 2
#define NROWS (T_TOK * KTOP)

typedef __attribute__((ext_vector_type(8))) short bf16x8;
typedef __attribute__((ext_vector_type(4))) float f32x4;

__device__ __forceinline__ unsigned short f2bf(float f) {
    unsigned u = __builtin_bit_cast(unsigned, f);
    u += 0x7fffu + ((u >> 16) & 1u);   // RNE
    return (unsigned short)(u >> 16);
}
__device__ __forceinline__ float bf2f(unsigned short h) {
    return __builtin_bit_cast(float, (unsigned)h << 16);
}

// async global->LDS, 16B per lane; LDS dest wave-uniform base + lane*16.
__device__ __forceinline__ void gll16(const unsigned short* g, const unsigned short* l) {
    __builtin_amdgcn_global_load_lds(
        (const __attribute__((address_space(1))) unsigned int*)g,
        (__attribute__((address_space(3))) unsigned int*)l, 16, 0, 0);
}

// ---------------- prep kernels ----------------

__global__ __launch_bounds__(256) void cvt_bf16_k(const float* __restrict__ in,
                                                  unsigned short* __restrict__ out, int n4) {
    int i = blockIdx.x * 256 + threadIdx.x;
    if (i >= n4) return;
    float4 v = ((const float4*)in)[i];
    ushort4 o;
    o.x = f2bf(v.x); o.y = f2bf(v.y); o.z = f2bf(v.z); o.w = f2bf(v.w);
    ((ushort4*)out)[i] = o;
}

// in: [nmat][R][C] f32  ->  out: [nmat][C][R] bf16
__global__ __launch_bounds__(256) void transpose_cast_k(const float* __restrict__ in,
                                                        unsigned short* __restrict__ out,
                                                        int R, int C) {
    __shared__ unsigned short tile[32][33];
    int m = blockIdx.z;
    const float* src = in + (size_t)m * R * C;
    unsigned short* dst = out + (size_t)m * R * C;
    int c0 = blockIdx.x * 32, r0 = blockIdx.y * 32;
    int tx = threadIdx.x & 31, ty = threadIdx.x >> 5;
#pragma unroll
    for (int i = 0; i < 32; i += 8)
        tile[ty + i][tx] = f2bf(src[(size_t)(r0 + ty + i) * C + c0 + tx]);
    __syncthreads();
#pragma unroll
    for (int i = 0; i < 32; i += 8)
        dst[(size_t)(c0 + ty + i) * R + r0 + tx] = tile[tx][ty + i];
}

// ---------------- 128x128 GEMM, deep pipeline, 2 blocks/CU ----------------------
// C = act(A @ Bt^T + bias). 256 thr = 4 waves (2Mx2N), per-wave 64x64 out.
// BK=32, 32 K-tiles, 4 LDS buffers (depth-3 pipeline), 64KB LDS -> 2 blocks/CU
// (cross-block overlap fills barrier/drain stalls; r5's 128KB was 1 block/CU).
// Counted vmcnt(8) per tile (never 0 until tail). Staging: gll16 linear dest +
// inverse-swizzled global source; reads apply same XOR (rule 21c) -> ~0 conflicts.
// LDS swizzle: rows packed 2-per-128B line; 16B-chunk ^= (line&7).
// T1: XCD-chunked map (1024 blocks, 128/XCD = exactly expert x's 16x8 tiles).
// VARIANT 0: out = acc + bias ;  VARIANT 1: out = silu(Gin) * (acc + bias)

constexpr int BMk = 128, BNk = 128, BKk = 32;
constexpr int NTk = DDIM / BKk;   // 32 K-tiles
// LDS ushort map: A buf b at b*4096 (8KB each, [0,32KB)); B buf b at 16384+b*4096.

template <int VARIANT>
__global__ __launch_bounds__(256) void gemm128_8p_k(
    const unsigned short* __restrict__ A, const int* __restrict__ rowidx, int lda,
    const unsigned short* __restrict__ Bt, const float* __restrict__ biasE,
    const unsigned short* __restrict__ Gin, unsigned short* __restrict__ Out,
    const int* __restrict__ offsets, int N, int K) {
    __shared__ __attribute__((aligned(16))) unsigned short lds[32768];  // 64 KiB

    // XCD-chunked map: 1024 blocks, 8 XCDs, 128 each; brow-major within chunk.
    const int nbn = N / BNk;                          // 8
    int l = (blockIdx.x & 7) * 128 + (blockIdx.x >> 3);
    int brow = l / nbn, bcol = l % nbn;
    int row0 = brow * BMk, col0 = bcol * BNk;
    int e = 0;
    while (offsets[e + 1] <= row0) ++e;

    const unsigned short* Bte = Bt + (size_t)e * N * K;
    const float* bias = biasE + (size_t)e * N;

    int tid = threadIdx.x;
    int lane = tid & 63, wid = tid >> 6;
    int wr = wid >> 1, wc = wid & 1;                  // 2x2 wave grid
    int l15 = lane & 15, l4 = lane >> 4;

    // ---- staging source mapping (inverse of LDS swizzle; rule 21c) ----
    // Within a 1024B group of 8 lines: lane i's linear slot (line=i>>3, phys
    // chunk=i&7) holds logical chunk c=(i&7)^(i>>3) of row 2*(i>>3)+(c>>2),
    // 16B col (c&3).
    int sc = (lane & 7) ^ (lane >> 3);
    int srow = ((lane >> 3) << 1) + (sc >> 2);        // 0..15 within group
    int scol = (sc & 3) * 8;                          // bf16 elems
    const unsigned short* asrc[2];
    const unsigned short* bsrc[2];
#pragma unroll
    for (int q = 0; q < 2; ++q) {
        int gr = row0 + (wid * 2 + q) * 16 + srow;    // 8 groups cover 128 rows
        int ar = rowidx ? rowidx[gr] : gr;
        asrc[q] = A + (size_t)ar * lda + scol;
        bsrc[q] = Bte + (size_t)(col0 + (wid * 2 + q) * 16 + srow) * K + scol;
    }
    unsigned adst[2], bdst[2];
#pragma unroll
    for (int q = 0; q < 2; ++q) {
        adst[q] = (wid * 2 + q) * 512;                // 1024B group per (wave,q)
        bdst[q] = 16384 + (wid * 2 + q) * 512;
    }

#define STAGE(t) { int _b = (t) & 3; int _k = (t) * BKk;              \
        gll16(asrc[0] + _k, lds + _b * 4096 + adst[0]);               \
        gll16(asrc[1] + _k, lds + _b * 4096 + adst[1]);               \
        gll16(bsrc[0] + _k, lds + _b * 4096 + bdst[0]);               \
        gll16(bsrc[1] + _k, lds + _b * 4096 + bdst[1]); }

    // ---- swizzled read offset (bytes within a line group) ----
    int rdoff = (l15 >> 1) * 128 + ((((l15 & 1) << 2) | l4) ^ (l15 >> 1)) * 16;

    f32x4 acc[4][4] = {};

    // prologue: stage tiles 0,1,2 (depth 3); wait tile 0 (8 newest = tiles 1,2)
    STAGE(0) STAGE(1) STAGE(2)
    asm volatile("s_waitcnt vmcnt(8)" ::: "memory");
    __builtin_amdgcn_s_barrier();

#pragma unroll 1
    for (int t = 0; t < NTk; ++t) {
        const char* Ab = (const char*)lds + (t & 3) * 8192;
        const char* Bb = (const char*)lds + 32768 + (t & 3) * 8192;
        bf16x8 af[4], bfr[4];
#pragma unroll
        for (int mi = 0; mi < 4; ++mi)
            af[mi] = *(const bf16x8*)(Ab + (wr * 32 + mi * 8) * 128 + rdoff);
#pragma unroll
        for (int ni = 0; ni < 4; ++ni)
            bfr[ni] = *(const bf16x8*)(Bb + (wc * 32 + ni * 8) * 128 + rdoff);
        if (t + 3 < NTk) STAGE(t + 3)
        __builtin_amdgcn_s_barrier();
        asm volatile("s_waitcnt lgkmcnt(0)" ::: "memory");
        __builtin_amdgcn_sched_barrier(0);
        __builtin_amdgcn_s_setprio(1);
#pragma unroll
        for (int mi = 0; mi < 4; ++mi)
#pragma unroll
            for (int ni = 0; ni < 4; ++ni)
                acc[mi][ni] = __builtin_amdgcn_mfma_f32_16x16x32_bf16(
                    af[mi], bfr[ni], acc[mi][ni], 0, 0, 0);
        __builtin_amdgcn_s_setprio(0);
        // tile boundary: counted vmcnt (tile t+1 must be landed; never 0 mid-loop)
        if (t < NTk - 1) {
            if (t + 3 < NTk)       asm volatile("s_waitcnt vmcnt(8)" ::: "memory");
            else if (t + 3 == NTk) asm volatile("s_waitcnt vmcnt(4)" ::: "memory");
            else                   asm volatile("s_waitcnt vmcnt(0)" ::: "memory");
            __builtin_amdgcn_s_barrier();
        }
    }
#undef STAGE

    float bv[4];
#pragma unroll
    for (int ni = 0; ni < 4; ++ni)
        bv[ni] = bias[col0 + wc * 64 + ni * 16 + l15];

#pragma unroll
    for (int mi = 0; mi < 4; ++mi) {
        int orow_b = row0 + wr * 64 + mi * 16 + l4 * 4;
#pragma unroll
        for (int ni = 0; ni < 4; ++ni) {
            int ocol = col0 + wc * 64 + ni * 16 + l15;
#pragma unroll
            for (int q = 0; q < 4; ++q) {
                size_t oidx = (size_t)(orow_b + q) * N + ocol;
                float v = acc[mi][ni][q] + bv[ni];
                if (VARIANT == 1) {
                    float g = bf2f(Gin[oidx]);
                    float s = g / (1.0f + __expf(-g));
                    v = s * v;
                }
                Out[oidx] = f2bf(v);
            }
        }
    }
}

// ---------------- combine ----------------

__global__ __launch_bounds__(256) void combine_k(
    const unsigned short* __restrict__ Y, const int* __restrict__ rev,
    const float* __restrict__ gates, const int* __restrict__ gidx,
    float* __restrict__ out) {
    int t = blockIdx.x;
    int r0 = rev[2 * t], r1 = rev[2 * t + 1];
    float g0 = gates[gidx[2 * t]], g1 = gates[gidx[2 * t + 1]];
    const unsigned short* y0 = Y + (size_t)r0 * DDIM;
    const unsigned short* y1 = Y + (size_t)r1 * DDIM;
    int d = threadIdx.x * 4;
    ushort4 a = *(const ushort4*)(y0 + d);
    ushort4 b = *(const ushort4*)(y1 + d);
    float4 r;
    r.x = g0 * bf2f(a.x) + g1 * bf2f(b.x);
    r.y = g0 * bf2f(a.y) + g1 * bf2f(b.y);
    r.z = g0 * bf2f(a.z) + g1 * bf2f(b.z);
    r.w = g0 * bf2f(a.w) + g1 * bf2f(b.w);
    *(float4*)(out + (size_t)t * DDIM + d) = r;
}

// ---------------- launch ----------------

extern "C" void kernel_launch(void* const* d_in, const int* in_sizes, int n_in,
                              void* d_out, int out_size, void* d_ws, size_t ws_size,
                              hipStream_t stream) {
    const int* offsets = (const int*)d_in[0];
    const float* jagged = (const float*)d_in[1];
    const float* weight = (const float*)d_in[2];
    const float* bias = (const float*)d_in[3];
    const int* index = (const int*)d_in[4];
    const float* weight_p = (const float*)d_in[5];
    const float* weight_out = (const float*)d_in[6];
    const int* rev = (const int*)d_in[7];
    const float* gates = (const float*)d_in[8];
    const int* gidx = (const int*)d_in[9];
    const float* bias_p = (const float*)d_in[10];
    const float* bias_out = (const float*)d_in[11];
    float* out = (float*)d_out;

    char* w = (char*)d_ws;
    unsigned short* jag_bf = (unsigned short*)w; w += (size_t)T_TOK * DDIM * 2;       // 16MB
    unsigned short* W1t    = (unsigned short*)w; w += (size_t)NEXP * DDIM * HDIM * 2; // 16MB
    unsigned short* Wpt    = (unsigned short*)w; w += (size_t)NEXP * DDIM * HDIM * 2; // 16MB
    unsigned short* Wot    = (unsigned short*)w; w += (size_t)NEXP * HDIM * DDIM * 2; // 16MB
    unsigned short* g_ws   = (unsigned short*)w; w += (size_t)NROWS * HDIM * 2;       // 32MB
    unsigned short* h_ws   = (unsigned short*)w; w += (size_t)NROWS * HDIM * 2;       // 32MB
    unsigned short* y_ws   = g_ws;   // g dead after u-GEMM epilogue; reuse for y

    // prep: bf16 cast + weight transposes (B^T layout)
    cvt_bf16_k<<<(T_TOK * DDIM / 4 + 255) / 256, 256, 0, stream>>>(jagged, jag_bf, T_TOK * DDIM / 4);
    transpose_cast_k<<<dim3(HDIM / 32, DDIM / 32, NEXP), 256, 0, stream>>>(weight, W1t, DDIM, HDIM);
    transpose_cast_k<<<dim3(HDIM / 32, DDIM / 32, NEXP), 256, 0, stream>>>(weight_p, Wpt, DDIM, HDIM);
    transpose_cast_k<<<dim3(DDIM / 32, HDIM / 32, NEXP), 256, 0, stream>>>(weight_out, Wot, HDIM, DDIM);

    const int grid = (NROWS / BMk) * (HDIM / BNk);    // 128 * 8 = 1024 blocks

    // g = gather(x) @ W + b
    gemm128_8p_k<0><<<grid, 256, 0, stream>>>(jag_bf, index, DDIM, W1t, bias, nullptr, g_ws,
                                              offsets, HDIM, DDIM);
    // h = silu(g) * (gather(x) @ Wp + bp)
    gemm128_8p_k<1><<<grid, 256, 0, stream>>>(jag_bf, index, DDIM, Wpt, bias_p, g_ws, h_ws,
                                              offsets, HDIM, DDIM);
    // y = h @ Wout + bout
    gemm128_8p_k<0><<<grid, 256, 0, stream>>>(h_ws, nullptr, HDIM, Wot, bias_out, nullptr, y_ws,
                                              offsets, DDIM, HDIM);
    // out[t] = sum_k gates[gidx[t,k]] * y[rev[t,k]]
    combine_k<<<T_TOK, 256, 0, stream>>>(y_ws, rev, gates, gidx, out);
}

// Round 7
// 180.917 us; speedup vs baseline: 1.1034x; 1.1034x over previous
//
#include <hip/hip_runtime.h>
#include <hip/hip_bf16.h>

#define T_TOK 8192
#define DDIM 1024
#define HDIM 1024
#define NEXP 8
#define KTOP 2
#define NROWS (T_TOK * KTOP)

typedef __attribute__((ext_vector_type(8))) short bf16x8;
typedef __attribute__((ext_vector_type(4))) float f32x4;

__device__ __forceinline__ unsigned short f2bf(float f) {
    unsigned u = __builtin_bit_cast(unsigned, f);
    u += 0x7fffu + ((u >> 16) & 1u);   // RNE
    return (unsigned short)(u >> 16);
}
__device__ __forceinline__ float bf2f(unsigned short h) {
    return __builtin_bit_cast(float, (unsigned)h << 16);
}

// async global->LDS, 16B per lane; LDS dest wave-uniform base + lane*16.
__device__ __forceinline__ void gll16(const unsigned short* g, const unsigned short* l) {
    __builtin_amdgcn_global_load_lds(
        (const __attribute__((address_space(1))) unsigned int*)g,
        (__attribute__((address_space(3))) unsigned int*)l, 16, 0, 0);
}

// ---------------- prep kernels ----------------

__global__ __launch_bounds__(256) void cvt_bf16_k(const float* __restrict__ in,
                                                  unsigned short* __restrict__ out, int n4) {
    int i = blockIdx.x * 256 + threadIdx.x;
    if (i >= n4) return;
    float4 v = ((const float4*)in)[i];
    ushort4 o;
    o.x = f2bf(v.x); o.y = f2bf(v.y); o.z = f2bf(v.z); o.w = f2bf(v.w);
    ((ushort4*)out)[i] = o;
}

// in: [nmat][R][C] f32  ->  out: [nmat][C][R] bf16
__global__ __launch_bounds__(256) void transpose_cast_k(const float* __restrict__ in,
                                                        unsigned short* __restrict__ out,
                                                        int R, int C) {
    __shared__ unsigned short tile[32][33];
    int m = blockIdx.z;
    const float* src = in + (size_t)m * R * C;
    unsigned short* dst = out + (size_t)m * R * C;
    int c0 = blockIdx.x * 32, r0 = blockIdx.y * 32;
    int tx = threadIdx.x & 31, ty = threadIdx.x >> 5;
#pragma unroll
    for (int i = 0; i < 32; i += 8)
        tile[ty + i][tx] = f2bf(src[(size_t)(r0 + ty + i) * C + c0 + tx]);
    __syncthreads();
#pragma unroll
    for (int i = 0; i < 32; i += 8)
        dst[(size_t)(c0 + ty + i) * R + r0 + tx] = tile[tx][ty + i];
}

// ---------------- 256x256 GEMM, deep pipeline, 1 barrier/tile ----------------
// C = act(A @ Bt^T + bias). 512 thr = 8 waves (2Mx4N), per-wave 128x64 out.
// BK=32, 32 K-tiles, 4 LDS buffers (depth-3), counted vmcnt(8) per tile.
// Per tile: stage(t+3) issue -> 12 ds_read_b128 -> lgkmcnt(0) -> 32 MFMA
// (setprio) -> vmcnt(8) -> ONE barrier. Race-safety: (WAR) stage(t+3) hits
// buf (t-1)&3, whose reads were lgkm-drained by each wave before its tile-(t-1)
// MFMA, hence before the end-of-(t-1) barrier; (RAW) per-wave counted vmcnt at
// the boundary + barrier publishes the landed DMA to all waves.
// Staging: gll16 linear dest + inverse-swizzled global source; reads apply the
// same XOR (rule 21c) -> ~0 conflicts. Rows packed 2/128B-line, chunk ^= line&7.
// T1: XCD-chunked map (XCD x owns expert x's rows).
// VARIANT 0: out = acc + bias ;  VARIANT 1: out = silu(Gin) * (acc + bias)

constexpr int BM2 = 256, BN2 = 256, BK2 = 32;
constexpr int NT2 = DDIM / BK2;   // 32 K-tiles
// LDS ushort map: A buf b at b*8192 (16KB each); B buf b at 32768 + b*8192.

template <int VARIANT>
__global__ __launch_bounds__(512) void gemm256_1b_k(
    const unsigned short* __restrict__ A, const int* __restrict__ rowidx, int lda,
    const unsigned short* __restrict__ Bt, const float* __restrict__ biasE,
    const unsigned short* __restrict__ Gin, unsigned short* __restrict__ Out,
    const int* __restrict__ offsets, int N, int K) {
    __shared__ __attribute__((aligned(16))) unsigned short lds[65536];  // 128 KiB

    // XCD-chunked map: 256 blocks, 8 XCDs, 32 each; brow-major within chunk.
    const int nbn = N / BN2;                          // 4
    int l = (blockIdx.x & 7) * 32 + (blockIdx.x >> 3);
    int brow = l / nbn, bcol = l % nbn;
    int row0 = brow * BM2, col0 = bcol * BN2;
    int e = 0;
    while (offsets[e + 1] <= row0) ++e;

    const unsigned short* Bte = Bt + (size_t)e * N * K;
    const float* bias = biasE + (size_t)e * N;

    int tid = threadIdx.x;
    int lane = tid & 63, wid = tid >> 6;
    int wm = wid >> 2, wn = wid & 3;                  // 2x4 wave grid
    int l15 = lane & 15, l4 = lane >> 4;

    // ---- staging source mapping (inverse of LDS swizzle; rule 21c) ----
    // Within a 1024B group of 8 lines: lane i's linear slot (line=i>>3, phys
    // chunk=i&7) holds logical chunk c=(i&7)^(i>>3) of row 2*(i>>3)+(c>>2),
    // 16B col (c&3).
    int sc = (lane & 7) ^ (lane >> 3);
    int srow = ((lane >> 3) << 1) + (sc >> 2);        // 0..15 within group
    int scol = (sc & 3) * 8;                          // bf16 elems
    const unsigned short* asrc[2];
    const unsigned short* bsrc[2];
#pragma unroll
    for (int q = 0; q < 2; ++q) {
        int gr = row0 + (wid * 2 + q) * 16 + srow;
        int ar = rowidx ? rowidx[gr] : gr;
        asrc[q] = A + (size_t)ar * lda + scol;
        bsrc[q] = Bte + (size_t)(col0 + (wid * 2 + q) * 16 + srow) * K + scol;
    }
    unsigned adst[2], bdst[2];
#pragma unroll
    for (int q = 0; q < 2; ++q) {
        adst[q] = (wid * 2 + q) * 512;                // 1024B group per (wave,q)
        bdst[q] = 32768 + (wid * 2 + q) * 512;
    }

#define STAGE(t) { int _b = (t) & 3; int _k = (t) * BK2;              \
        gll16(asrc[0] + _k, lds + _b * 8192 + adst[0]);               \
        gll16(asrc[1] + _k, lds + _b * 8192 + adst[1]);               \
        gll16(bsrc[0] + _k, lds + _b * 8192 + bdst[0]);               \
        gll16(bsrc[1] + _k, lds + _b * 8192 + bdst[1]); }

    // ---- swizzled read offset (bytes within a line group) ----
    int rdoff = (l15 >> 1) * 128 + ((((l15 & 1) << 2) | l4) ^ (l15 >> 1)) * 16;

    f32x4 acc[8][4] = {};

    // prologue: stage tiles 0,1,2 (depth 3); wait tile 0 (8 newest = tiles 1,2)
    STAGE(0) STAGE(1) STAGE(2)
    asm volatile("s_waitcnt vmcnt(8)" ::: "memory");
    __builtin_amdgcn_s_barrier();

#pragma unroll 1
    for (int t = 0; t < NT2; ++t) {
        const char* Ab = (const char*)lds + (t & 3) * 16384;
        const char* Bb = (const char*)lds + 65536 + (t & 3) * 16384;
        if (t + 3 < NT2) STAGE(t + 3)
        bf16x8 af[8], bfr[4];
#pragma unroll
        for (int mi = 0; mi < 8; ++mi)
            af[mi] = *(const bf16x8*)(Ab + (wm * 64 + mi * 8) * 128 + rdoff);
#pragma unroll
        for (int ni = 0; ni < 4; ++ni)
            bfr[ni] = *(const bf16x8*)(Bb + (wn * 32 + ni * 8) * 128 + rdoff);
        asm volatile("s_waitcnt lgkmcnt(0)" ::: "memory");
        __builtin_amdgcn_sched_barrier(0);
        __builtin_amdgcn_s_setprio(1);
#pragma unroll
        for (int mi = 0; mi < 8; ++mi)
#pragma unroll
            for (int ni = 0; ni < 4; ++ni)
                acc[mi][ni] = __builtin_amdgcn_mfma_f32_16x16x32_bf16(
                    af[mi], bfr[ni], acc[mi][ni], 0, 0, 0);
        __builtin_amdgcn_s_setprio(0);
        // tile boundary: counted vmcnt (tile t+1 must be landed; never 0 mid-loop)
        if (t < NT2 - 1) {
            if (t + 3 < NT2)       asm volatile("s_waitcnt vmcnt(8)" ::: "memory");
            else if (t + 3 == NT2) asm volatile("s_waitcnt vmcnt(4)" ::: "memory");
            else                   asm volatile("s_waitcnt vmcnt(0)" ::: "memory");
            __builtin_amdgcn_s_barrier();
        }
    }
#undef STAGE

    float bv[4];
#pragma unroll
    for (int ni = 0; ni < 4; ++ni)
        bv[ni] = bias[col0 + wn * 64 + ni * 16 + l15];

#pragma unroll
    for (int mi = 0; mi < 8; ++mi) {
        int orow_b = row0 + wm * 128 + mi * 16 + l4 * 4;
#pragma unroll
        for (int ni = 0; ni < 4; ++ni) {
            int ocol = col0 + wn * 64 + ni * 16 + l15;
#pragma unroll
            for (int q = 0; q < 4; ++q) {
                size_t oidx = (size_t)(orow_b + q) * N + ocol;
                float v = acc[mi][ni][q] + bv[ni];
                if (VARIANT == 1) {
                    float g = bf2f(Gin[oidx]);
                    float s = g / (1.0f + __expf(-g));
                    v = s * v;
                }
                Out[oidx] = f2bf(v);
            }
        }
    }
}

// ---------------- combine ----------------

__global__ __launch_bounds__(256) void combine_k(
    const unsigned short* __restrict__ Y, const int* __restrict__ rev,
    const float* __restrict__ gates, const int* __restrict__ gidx,
    float* __restrict__ out) {
    int t = blockIdx.x;
    int r0 = rev[2 * t], r1 = rev[2 * t + 1];
    float g0 = gates[gidx[2 * t]], g1 = gates[gidx[2 * t + 1]];
    const unsigned short* y0 = Y + (size_t)r0 * DDIM;
    const unsigned short* y1 = Y + (size_t)r1 * DDIM;
    int d = threadIdx.x * 4;
    ushort4 a = *(const ushort4*)(y0 + d);
    ushort4 b = *(const ushort4*)(y1 + d);
    float4 r;
    r.x = g0 * bf2f(a.x) + g1 * bf2f(b.x);
    r.y = g0 * bf2f(a.y) + g1 * bf2f(b.y);
    r.z = g0 * bf2f(a.z) + g1 * bf2f(b.z);
    r.w = g0 * bf2f(a.w) + g1 * bf2f(b.w);
    *(float4*)(out + (size_t)t * DDIM + d) = r;
}

// ---------------- launch ----------------

extern "C" void kernel_launch(void* const* d_in, const int* in_sizes, int n_in,
                              void* d_out, int out_size, void* d_ws, size_t ws_size,
                              hipStream_t stream) {
    const int* offsets = (const int*)d_in[0];
    const float* jagged = (const float*)d_in[1];
    const float* weight = (const float*)d_in[2];
    const float* bias = (const float*)d_in[3];
    const int* index = (const int*)d_in[4];
    const float* weight_p = (const float*)d_in[5];
    const float* weight_out = (const float*)d_in[6];
    const int* rev = (const int*)d_in[7];
    const float* gates = (const float*)d_in[8];
    const int* gidx = (const int*)d_in[9];
    const float* bias_p = (const float*)d_in[10];
    const float* bias_out = (const float*)d_in[11];
    float* out = (float*)d_out;

    char* w = (char*)d_ws;
    unsigned short* jag_bf = (unsigned short*)w; w += (size_t)T_TOK * DDIM * 2;       // 16MB
    unsigned short* W1t    = (unsigned short*)w; w += (size_t)NEXP * DDIM * HDIM * 2; // 16MB
    unsigned short* Wpt    = (unsigned short*)w; w += (size_t)NEXP * DDIM * HDIM * 2; // 16MB
    unsigned short* Wot    = (unsigned short*)w; w += (size_t)NEXP * HDIM * DDIM * 2; // 16MB
    unsigned short* g_ws   = (unsigned short*)w; w += (size_t)NROWS * HDIM * 2;       // 32MB
    unsigned short* h_ws   = (unsigned short*)w; w += (size_t)NROWS * HDIM * 2;       // 32MB
    unsigned short* y_ws   = g_ws;   // g dead after u-GEMM epilogue; reuse for y

    // prep: bf16 cast + weight transposes (B^T layout)
    cvt_bf16_k<<<(T_TOK * DDIM / 4 + 255) / 256, 256, 0, stream>>>(jagged, jag_bf, T_TOK * DDIM / 4);
    transpose_cast_k<<<dim3(HDIM / 32, DDIM / 32, NEXP), 256, 0, stream>>>(weight, W1t, DDIM, HDIM);
    transpose_cast_k<<<dim3(HDIM / 32, DDIM / 32, NEXP), 256, 0, stream>>>(weight_p, Wpt, DDIM, HDIM);
    transpose_cast_k<<<dim3(DDIM / 32, HDIM / 32, NEXP), 256, 0, stream>>>(weight_out, Wot, HDIM, DDIM);

    const int grid = (NROWS / BM2) * (HDIM / BN2);    // 64 * 4 = 256 blocks

    // g = gather(x) @ W + b
    gemm256_1b_k<0><<<grid, 512, 0, stream>>>(jag_bf, index, DDIM, W1t, bias, nullptr, g_ws,
                                              offsets, HDIM, DDIM);
    // h = silu(g) * (gather(x) @ Wp + bp)
    gemm256_1b_k<1><<<grid, 512, 0, stream>>>(jag_bf, index, DDIM, Wpt, bias_p, g_ws, h_ws,
                                              offsets, HDIM, DDIM);
    // y = h @ Wout + bout
    gemm256_1b_k<0><<<grid, 512, 0, stream>>>(h_ws, nullptr, HDIM, Wot, bias_out, nullptr, y_ws,
                                              offsets, DDIM, HDIM);
    // out[t] = sum_k gates[gidx[t,k]] * y[rev[t,k]]
    combine_k<<<T_TOK, 256, 0, stream>>>(y_ws, rev, gates, gidx, out);
}

// Round 8
// 180.149 us; speedup vs baseline: 1.1081x; 1.0043x over previous
//
#include <hip/hip_runtime.h>
#include <hip/hip_bf16.h>

#define T_TOK 8192
#define DDIM 1024
#define HDIM 1024
#define NEXP 8
#define KTOP 2
#define NROWS (T_TOK * KTOP)

typedef __attribute__((ext_vector_type(8))) short bf16x8;
typedef __attribute__((ext_vector_type(4))) float f32x4;

__device__ __forceinline__ unsigned short f2bf(float f) {
    unsigned u = __builtin_bit_cast(unsigned, f);
    u += 0x7fffu + ((u >> 16) & 1u);   // RNE
    return (unsigned short)(u >> 16);
}
__device__ __forceinline__ float bf2f(unsigned short h) {
    return __builtin_bit_cast(float, (unsigned)h << 16);
}

// async global->LDS, 16B per lane; LDS dest wave-uniform base + lane*16.
__device__ __forceinline__ void gll16(const unsigned short* g, const unsigned short* l) {
    __builtin_amdgcn_global_load_lds(
        (const __attribute__((address_space(1))) unsigned int*)g,
        (__attribute__((address_space(3))) unsigned int*)l, 16, 0, 0);
}

// ---------------- prep kernels ----------------

__global__ __launch_bounds__(256) void cvt_bf16_k(const float* __restrict__ in,
                                                  unsigned short* __restrict__ out, int n4) {
    int i = blockIdx.x * 256 + threadIdx.x;
    if (i >= n4) return;
    float4 v = ((const float4*)in)[i];
    ushort4 o;
    o.x = f2bf(v.x); o.y = f2bf(v.y); o.z = f2bf(v.z); o.w = f2bf(v.w);
    ((ushort4*)out)[i] = o;
}

// in: [nmat][R][C] f32  ->  out: [nmat][C][R] bf16
__global__ __launch_bounds__(256) void transpose_cast_k(const float* __restrict__ in,
                                                        unsigned short* __restrict__ out,
                                                        int R, int C) {
    __shared__ unsigned short tile[32][33];
    int m = blockIdx.z;
    const float* src = in + (size_t)m * R * C;
    unsigned short* dst = out + (size_t)m * R * C;
    int c0 = blockIdx.x * 32, r0 = blockIdx.y * 32;
    int tx = threadIdx.x & 31, ty = threadIdx.x >> 5;
#pragma unroll
    for (int i = 0; i < 32; i += 8)
        tile[ty + i][tx] = f2bf(src[(size_t)(r0 + ty + i) * C + c0 + tx]);
    __syncthreads();
#pragma unroll
    for (int i = 0; i < 32; i += 8)
        dst[(size_t)(c0 + ty + i) * R + r0 + tx] = tile[tx][ty + i];
}

// ---------------- 256x256 GEMM, reg-double-buffered deep pipeline ---------------
// C = act(A @ Bt^T + bias). 512 thr = 8 waves (2Mx4N), per-wave 128x64 out.
// BK=32, 32 K-tiles, 4 LDS bufs, stage distance 3, counted vmcnt(4)/tile.
// Per tile t: read A-half0(4) -> lgkm(0) -> MFMA1(16) -> read A-half1(4) +
// prefetch B(t+1)(4, reg-dbuf fbA/fbB) -> lgkmcnt(4) counted -> MFMA2(16)
// -> vmcnt(4) -> barrier. Only 4 ds_reads exposed per tile; the other 8 run
// under the MFMA clusters (LDS pipe || MFMA pipe, m114).
// Race-safety: STAGE(t+3)->buf (t-1)&3: all waves' reads of tile t-1 drained
// (lgkm) before barrier end-of-(t-1), stage issued after it. B(t+1) prefetch
// reads buf (t+1)&3, drained at next sub-iter's lgkm(0) before barrier
// end-of-(t+1), and its overwrite (stage t+5) issues at sub-iter t+2. RAW:
// boundary vmcnt(4)+barrier publishes tile t+2 for sub-iter t+1's prefetch.
// Staging: gll16 linear dest + inverse-swizzled global src; reads same XOR
// (rule 21c) -> ~0 conflicts. Rows packed 2/128B-line, chunk ^= line&7.
// T1: XCD-chunked map (XCD x owns expert x's rows).
// VARIANT 0: out = acc + bias ;  VARIANT 1: out = silu(Gin) * (acc + bias)

constexpr int BM2 = 256, BN2 = 256, BK2 = 32;
constexpr int NT2 = DDIM / BK2;   // 32 K-tiles
// LDS ushort map: A buf b at b*8192 (16KB each); B buf b at 32768 + b*8192.

template <int VARIANT>
__global__ __launch_bounds__(512) void gemm256_dp_k(
    const unsigned short* __restrict__ A, const int* __restrict__ rowidx, int lda,
    const unsigned short* __restrict__ Bt, const float* __restrict__ biasE,
    const unsigned short* __restrict__ Gin, unsigned short* __restrict__ Out,
    const int* __restrict__ offsets, int N, int K) {
    __shared__ __attribute__((aligned(16))) unsigned short lds[65536];  // 128 KiB

    // XCD-chunked map: 256 blocks, 8 XCDs, 32 each; brow-major within chunk.
    const int nbn = N / BN2;                          // 4
    int l = (blockIdx.x & 7) * 32 + (blockIdx.x >> 3);
    int brow = l / nbn, bcol = l % nbn;
    int row0 = brow * BM2, col0 = bcol * BN2;
    int e = 0;
    while (offsets[e + 1] <= row0) ++e;

    const unsigned short* Bte = Bt + (size_t)e * N * K;
    const float* bias = biasE + (size_t)e * N;

    int tid = threadIdx.x;
    int lane = tid & 63, wid = tid >> 6;
    int wm = wid >> 2, wn = wid & 3;                  // 2x4 wave grid
    int l15 = lane & 15, l4 = lane >> 4;

    // ---- staging source mapping (inverse of LDS swizzle; rule 21c) ----
    int sc = (lane & 7) ^ (lane >> 3);
    int srow = ((lane >> 3) << 1) + (sc >> 2);        // 0..15 within group
    int scol = (sc & 3) * 8;                          // bf16 elems
    const unsigned short* asrc[2];
    const unsigned short* bsrc[2];
#pragma unroll
    for (int q = 0; q < 2; ++q) {
        int gr = row0 + (wid * 2 + q) * 16 + srow;
        int ar = rowidx ? rowidx[gr] : gr;
        asrc[q] = A + (size_t)ar * lda + scol;
        bsrc[q] = Bte + (size_t)(col0 + (wid * 2 + q) * 16 + srow) * K + scol;
    }
    unsigned adst[2], bdst[2];
#pragma unroll
    for (int q = 0; q < 2; ++q) {
        adst[q] = (wid * 2 + q) * 512;                // 1024B group per (wave,q)
        bdst[q] = 32768 + (wid * 2 + q) * 512;
    }

#define STAGE(t) { int _b = (t) & 3; int _k = (t) * BK2;              \
        gll16(asrc[0] + _k, lds + _b * 8192 + adst[0]);               \
        gll16(asrc[1] + _k, lds + _b * 8192 + adst[1]);               \
        gll16(bsrc[0] + _k, lds + _b * 8192 + bdst[0]);               \
        gll16(bsrc[1] + _k, lds + _b * 8192 + bdst[1]); }

    // ---- swizzled read offset (bytes within a line group) ----
    int rdoff = (l15 >> 1) * 128 + ((((l15 & 1) << 2) | l4) ^ (l15 >> 1)) * 16;

    f32x4 acc[8][4] = {};
    bf16x8 fbA[4], fbB[4];

    // prologue: stage tiles 0,1,2 (distance 3); tiles 0,1 landed at vmcnt(4)
    STAGE(0) STAGE(1) STAGE(2)
    asm volatile("s_waitcnt vmcnt(4)" ::: "memory");
    __builtin_amdgcn_s_barrier();
#pragma unroll
    for (int ni = 0; ni < 4; ++ni)
        fbA[ni] = *(const bf16x8*)((const char*)lds + 65536 + (wn * 32 + ni * 8) * 128 + rdoff);

    // SUBITER(T): fb-cur = FBC, fb-next (prefetch B(T+1)) = FBN
#define SUBITER(T, FBC, FBN)                                              \
    {                                                                     \
        const char* Ab_ = (const char*)lds + ((T) & 3) * 16384;           \
        bf16x8 fa[4], fa2[4];                                             \
        _Pragma("unroll") for (int mi = 0; mi < 4; ++mi)                  \
            fa[mi] = *(const bf16x8*)(Ab_ + (wm * 64 + mi * 8) * 128 + rdoff); \
        if ((T) + 3 < NT2) STAGE((T) + 3)                                 \
        asm volatile("s_waitcnt lgkmcnt(0)" ::: "memory");                \
        __builtin_amdgcn_sched_barrier(0);                                \
        __builtin_amdgcn_s_setprio(1);                                    \
        _Pragma("unroll") for (int mi = 0; mi < 4; ++mi)                  \
        _Pragma("unroll") for (int ni = 0; ni < 4; ++ni)                  \
            acc[mi][ni] = __builtin_amdgcn_mfma_f32_16x16x32_bf16(        \
                fa[mi], FBC[ni], acc[mi][ni], 0, 0, 0);                   \
        __builtin_amdgcn_s_setprio(0);                                    \
        _Pragma("unroll") for (int mi = 0; mi < 4; ++mi)                  \
            fa2[mi] = *(const bf16x8*)(Ab_ + (wm * 64 + 32 + mi * 8) * 128 + rdoff); \
        if ((T) + 1 < NT2) {                                              \
            const char* Bb_ = (const char*)lds + 65536 + (((T) + 1) & 3) * 16384; \
            _Pragma("unroll") for (int ni = 0; ni < 4; ++ni)              \
                FBN[ni] = *(const bf16x8*)(Bb_ + (wn * 32 + ni * 8) * 128 + rdoff); \
            asm volatile("s_waitcnt lgkmcnt(4)" ::: "memory");            \
        } else {                                                          \
            asm volatile("s_waitcnt lgkmcnt(0)" ::: "memory");            \
        }                                                                 \
        __builtin_amdgcn_sched_barrier(0);                                \
        __builtin_amdgcn_s_setprio(1);                                    \
        _Pragma("unroll") for (int mi = 0; mi < 4; ++mi)                  \
        _Pragma("unroll") for (int ni = 0; ni < 4; ++ni)                  \
            acc[4 + mi][ni] = __builtin_amdgcn_mfma_f32_16x16x32_bf16(    \
                fa2[mi], FBC[ni], acc[4 + mi][ni], 0, 0, 0);              \
        __builtin_amdgcn_s_setprio(0);                                    \
        if ((T) + 2 < NT2) {                                              \
            if ((T) + 3 < NT2) asm volatile("s_waitcnt vmcnt(4)" ::: "memory"); \
            else               asm volatile("s_waitcnt vmcnt(0)" ::: "memory"); \
            __builtin_amdgcn_s_barrier();                                 \
        }                                                                 \
    }

#pragma unroll 1
    for (int i = 0; i < NT2 / 2; ++i) {
        SUBITER(2 * i,     fbA, fbB)
        SUBITER(2 * i + 1, fbB, fbA)
    }
#undef SUBITER
#undef STAGE

    float bv[4];
#pragma unroll
    for (int ni = 0; ni < 4; ++ni)
        bv[ni] = bias[col0 + wn * 64 + ni * 16 + l15];

#pragma unroll
    for (int mi = 0; mi < 8; ++mi) {
        int orow_b = row0 + wm * 128 + mi * 16 + l4 * 4;
#pragma unroll
        for (int ni = 0; ni < 4; ++ni) {
            int ocol = col0 + wn * 64 + ni * 16 + l15;
#pragma unroll
            for (int q = 0; q < 4; ++q) {
                size_t oidx = (size_t)(orow_b + q) * N + ocol;
                float v = acc[mi][ni][q] + bv[ni];
                if (VARIANT == 1) {
                    float g = bf2f(Gin[oidx]);
                    float s = g / (1.0f + __expf(-g));
                    v = s * v;
                }
                Out[oidx] = f2bf(v);
            }
        }
    }
}

// ---------------- combine ----------------

__global__ __launch_bounds__(256) void combine_k(
    const unsigned short* __restrict__ Y, const int* __restrict__ rev,
    const float* __restrict__ gates, const int* __restrict__ gidx,
    float* __restrict__ out) {
    int t = blockIdx.x;
    int r0 = rev[2 * t], r1 = rev[2 * t + 1];
    float g0 = gates[gidx[2 * t]], g1 = gates[gidx[2 * t + 1]];
    const unsigned short* y0 = Y + (size_t)r0 * DDIM;
    const unsigned short* y1 = Y + (size_t)r1 * DDIM;
    int d = threadIdx.x * 4;
    ushort4 a = *(const ushort4*)(y0 + d);
    ushort4 b = *(const ushort4*)(y1 + d);
    float4 r;
    r.x = g0 * bf2f(a.x) + g1 * bf2f(b.x);
    r.y = g0 * bf2f(a.y) + g1 * bf2f(b.y);
    r.z = g0 * bf2f(a.z) + g1 * bf2f(b.z);
    r.w = g0 * bf2f(a.w) + g1 * bf2f(b.w);
    *(float4*)(out + (size_t)t * DDIM + d) = r;
}

// ---------------- launch ----------------

extern "C" void kernel_launch(void* const* d_in, const int* in_sizes, int n_in,
                              void* d_out, int out_size, void* d_ws, size_t ws_size,
                              hipStream_t stream) {
    const int* offsets = (const int*)d_in[0];
    const float* jagged = (const float*)d_in[1];
    const float* weight = (const float*)d_in[2];
    const float* bias = (const float*)d_in[3];
    const int* index = (const int*)d_in[4];
    const float* weight_p = (const float*)d_in[5];
    const float* weight_out = (const float*)d_in[6];
    const int* rev = (const int*)d_in[7];
    const float* gates = (const float*)d_in[8];
    const int* gidx = (const int*)d_in[9];
    const float* bias_p = (const float*)d_in[10];
    const float* bias_out = (const float*)d_in[11];
    float* out = (float*)d_out;

    char* w = (char*)d_ws;
    unsigned short* jag_bf = (unsigned short*)w; w += (size_t)T_TOK * DDIM * 2;       // 16MB
    unsigned short* W1t    = (unsigned short*)w; w += (size_t)NEXP * DDIM * HDIM * 2; // 16MB
    unsigned short* Wpt    = (unsigned short*)w; w += (size_t)NEXP * DDIM * HDIM * 2; // 16MB
    unsigned short* Wot    = (unsigned short*)w; w += (size_t)NEXP * HDIM * DDIM * 2; // 16MB
    unsigned short* g_ws   = (unsigned short*)w; w += (size_t)NROWS * HDIM * 2;       // 32MB
    unsigned short* h_ws   = (unsigned short*)w; w += (size_t)NROWS * HDIM * 2;       // 32MB
    unsigned short* y_ws   = g_ws;   // g dead after u-GEMM epilogue; reuse for y

    // prep: bf16 cast + weight transposes (B^T layout)
    cvt_bf16_k<<<(T_TOK * DDIM / 4 + 255) / 256, 256, 0, stream>>>(jagged, jag_bf, T_TOK * DDIM / 4);
    transpose_cast_k<<<dim3(HDIM / 32, DDIM / 32, NEXP), 256, 0, stream>>>(weight, W1t, DDIM, HDIM);
    transpose_cast_k<<<dim3(HDIM / 32, DDIM / 32, NEXP), 256, 0, stream>>>(weight_p, Wpt, DDIM, HDIM);
    transpose_cast_k<<<dim3(DDIM / 32, HDIM / 32, NEXP), 256, 0, stream>>>(weight_out, Wot, HDIM, DDIM);

    const int grid = (NROWS / BM2) * (HDIM / BN2);    // 64 * 4 = 256 blocks

    // g = gather(x) @ W + b
    gemm256_dp_k<0><<<grid, 512, 0, stream>>>(jag_bf, index, DDIM, W1t, bias, nullptr, g_ws,
                                              offsets, HDIM, DDIM);
    // h = silu(g) * (gather(x) @ Wp + bp)
    gemm256_dp_k<1><<<grid, 512, 0, stream>>>(jag_bf, index, DDIM, Wpt, bias_p, g_ws, h_ws,
                                              offsets, HDIM, DDIM);
    // y = h @ Wout + bout
    gemm256_dp_k<0><<<grid, 512, 0, stream>>>(h_ws, nullptr, HDIM, Wot, bias_out, nullptr, y_ws,
                                              offsets, DDIM, HDIM);
    // out[t] = sum_k gates[gidx[t,k]] * y[rev[t,k]]
    combine_k<<<T_TOK, 256, 0, stream>>>(y_ws, rev, gates, gidx, out);
}